// Round 5
// baseline (270.736 us; speedup 1.0000x reference)
//
#include <hip/hip_runtime.h>

#define B_TOTAL 32768
#define NF 200
#define D_IN 5
#define NH 15
#define NOUT 30
#define NOP 16            // o-pair slots per f: 15 real + 1 zero-pad lane

// rec2 layout: [f][j(0..3)][op(0..15)][4 floats] = 256 floats (1 KB) per f.
//   j=0: {bc0, bc1, w3_0, w3_1}
//   j=1: {Wc[0][o0], Wc[0][o1], Wc[1][o0], Wc[1][o1]}
//   j=2: {Wc[2][o0], Wc[2][o1], Wc[3][o0], Wc[3][o1]}
//   j=3: {Wc[4][o0], Wc[4][o1], 0, 0}
// op==15 -> all zeros (pad lane computes zeros, contributes nothing).

typedef float v2f __attribute__((ext_vector_type(2)));
typedef float v4f __attribute__((ext_vector_type(4)));

__global__ __launch_bounds__(256) void precompute_kernel(
    const float* __restrict__ W1, const float* __restrict__ b1,
    const float* __restrict__ W2, const float* __restrict__ b2,
    const float* __restrict__ W3, float* __restrict__ rec2)
{
    const int idx = blockIdx.x * 256 + threadIdx.x;
    if (idx >= NF * NOP) return;
    const int f  = idx / NOP;
    const int op = idx - f * NOP;
    float* r = rec2 + (size_t)f * 256;

    if (op == 15) {
        #pragma unroll
        for (int j = 0; j < 4; ++j) {
            r[j * 64 + op * 4 + 0] = 0.f; r[j * 64 + op * 4 + 1] = 0.f;
            r[j * 64 + op * 4 + 2] = 0.f; r[j * 64 + op * 4 + 3] = 0.f;
        }
        return;
    }
    const int o0 = 2 * op, o1 = 2 * op + 1;

    float bcv[2], wc[D_IN][2];
    #pragma unroll
    for (int t = 0; t < 2; ++t) {
        const int o = (t == 0) ? o0 : o1;
        float s = b2[f * NOUT + o];
        #pragma unroll
        for (int h = 0; h < NH; ++h)
            s = fmaf(b1[f * NH + h], W2[(f * NH + h) * NOUT + o], s);
        bcv[t] = s;
        #pragma unroll
        for (int i = 0; i < D_IN; ++i) {
            float w = 0.f;
            #pragma unroll
            for (int h = 0; h < NH; ++h)
                w = fmaf(W1[(f * D_IN + i) * NH + h], W2[(f * NH + h) * NOUT + o], w);
            wc[i][t] = w;
        }
    }
    // j=0
    r[0 * 64 + op * 4 + 0] = bcv[0];
    r[0 * 64 + op * 4 + 1] = bcv[1];
    r[0 * 64 + op * 4 + 2] = W3[f * NOUT + o0];
    r[0 * 64 + op * 4 + 3] = W3[f * NOUT + o1];
    // j=1
    r[1 * 64 + op * 4 + 0] = wc[0][0];
    r[1 * 64 + op * 4 + 1] = wc[0][1];
    r[1 * 64 + op * 4 + 2] = wc[1][0];
    r[1 * 64 + op * 4 + 3] = wc[1][1];
    // j=2
    r[2 * 64 + op * 4 + 0] = wc[2][0];
    r[2 * 64 + op * 4 + 1] = wc[2][1];
    r[2 * 64 + op * 4 + 2] = wc[3][0];
    r[2 * 64 + op * 4 + 3] = wc[3][1];
    // j=3
    r[3 * 64 + op * 4 + 0] = wc[4][0];
    r[3 * 64 + op * 4 + 1] = wc[4][1];
    r[3 * 64 + op * 4 + 2] = 0.f;
    r[3 * 64 + op * 4 + 3] = 0.f;
}

// ---------------- Main kernel ----------------
// Block: 256 thr (4 waves) = 64 batch rows x 40 f (f-part = blockIdx.y).
// Lane = (b_sub 0..3, op 0..15); each lane owns 4 batch rows and 1 o-pair.
// Weights: LDS (staged once, ds_read_b128 per f, 2-way bank alias = free).
// y: per-lane global dwordx4, immediate offsets, 20 loads in flight per group.
// No barriers / s_loads in the hot loop.
#define FPART 40
#define NPARTS 5

__global__ __launch_bounds__(256, 3) void mlp_kernel(
    const float* __restrict__ y, const float* __restrict__ rec2,
    const float* __restrict__ b3, float* __restrict__ out)
{
    __shared__ v4f shw[FPART * 4 * NOP];   // 2560 v4f = 40 KB

    const int tid = threadIdx.x;
    const int f0  = blockIdx.y * FPART;

    // ---- stage this f-part's weights into LDS (linear, coalesced)
    {
        const v4f* gsrc = (const v4f*)(rec2 + (size_t)f0 * 256);
        #pragma unroll
        for (int i = 0; i < 10; ++i)
            shw[tid + i * 256] = gsrc[tid + i * 256];
    }

    const int l   = tid & 63;
    const int wv  = tid >> 6;
    const int bsu = l >> 4;
    const int op  = l & 15;
    const int bb  = blockIdx.x * 64 + wv * 16 + bsu * 4;   // lane's first b

    const v4f* yr[4];
    #pragma unroll
    for (int bl = 0; bl < 4; ++bl)
        yr[bl] = (const v4f*)(y + (size_t)(bb + bl) * (NF * D_IN) + f0 * D_IN);

    v2f acc[4] = {(v2f)0.f, (v2f)0.f, (v2f)0.f, (v2f)0.f};

    __syncthreads();

    #pragma unroll 1
    for (int g = 0; g < FPART / 4; ++g) {
        // 4 rows x 20 floats for this 4-f group (all independent loads)
        v4f yv[4][5];
        #pragma unroll
        for (int bl = 0; bl < 4; ++bl)
            #pragma unroll
            for (int j = 0; j < 5; ++j)
                yv[bl][j] = yr[bl][g * 5 + j];

        #pragma unroll
        for (int k = 0; k < 4; ++k) {
            const int fl = g * 4 + k;
            const v4f w0  = shw[(fl * 4 + 0) * NOP + op];
            const v4f w1  = shw[(fl * 4 + 1) * NOP + op];
            const v4f w2  = shw[(fl * 4 + 2) * NOP + op];
            const v4f w3q = shw[(fl * 4 + 3) * NOP + op];

            #pragma unroll
            for (int bl = 0; bl < 4; ++bl) {
                const float yb0 = yv[bl][(k * 5 + 0) >> 2][(k * 5 + 0) & 3];
                const float yb1 = yv[bl][(k * 5 + 1) >> 2][(k * 5 + 1) & 3];
                const float yb2 = yv[bl][(k * 5 + 2) >> 2][(k * 5 + 2) & 3];
                const float yb3 = yv[bl][(k * 5 + 3) >> 2][(k * 5 + 3) & 3];
                const float yb4 = yv[bl][(k * 5 + 4) >> 2][(k * 5 + 4) & 3];

                v2f z = (v2f){w0.x, w0.y} + yb0 * (v2f){w1.x, w1.y};
                z += yb1 * (v2f){w1.z, w1.w};
                z += yb2 * (v2f){w2.x, w2.y};
                z += yb3 * (v2f){w2.z, w2.w};
                z += yb4 * (v2f){w3q.x, w3q.y};
                z  = __builtin_elementwise_max(z, (v2f)0.0f);   // v_pk_max_f32
                acc[bl] += z * (v2f){w0.z, w0.w};
            }
        }
    }

    // ---- reduce over the 16 op-lanes (butterfly; pad lane holds zeros)
    float s0 = acc[0].x + acc[0].y;
    float s1 = acc[1].x + acc[1].y;
    float s2 = acc[2].x + acc[2].y;
    float s3 = acc[3].x + acc[3].y;
    #pragma unroll
    for (int m = 1; m < 16; m <<= 1) {
        s0 += __shfl_xor(s0, m, 16);
        s1 += __shfl_xor(s1, m, 16);
        s2 += __shfl_xor(s2, m, 16);
        s3 += __shfl_xor(s3, m, 16);
    }
    if (op < 4) {
        float v = (op == 0) ? s0 : (op == 1) ? s1 : (op == 2) ? s2 : s3;
        if (blockIdx.y == 0) v += b3[0];
        atomicAdd(&out[bb + op], v);
    }
}

extern "C" void kernel_launch(void* const* d_in, const int* in_sizes, int n_in,
                              void* d_out, int out_size, void* d_ws, size_t ws_size,
                              hipStream_t stream) {
    const float* y  = (const float*)d_in[0];
    const float* W1 = (const float*)d_in[1];
    const float* b1 = (const float*)d_in[2];
    const float* W2 = (const float*)d_in[3];
    const float* b2 = (const float*)d_in[4];
    const float* W3 = (const float*)d_in[5];
    const float* b3 = (const float*)d_in[6];
    float* out = (float*)d_out;

    float* rec2 = (float*)d_ws;   // 200 * 256 floats = 204.8 KB

    hipMemsetAsync(out, 0, (size_t)B_TOTAL * sizeof(float), stream);
    precompute_kernel<<<(NF * NOP + 255) / 256, 256, 0, stream>>>(W1, b1, W2, b2, W3, rec2);
    mlp_kernel<<<dim3(B_TOTAL / 64, NPARTS), 256, 0, stream>>>(y, rec2, b3, out);
}

// Round 6
// 246.249 us; speedup vs baseline: 1.0994x; 1.0994x over previous
//
#include <hip/hip_runtime.h>

#define B_TOTAL 32768
#define NF 200
#define D_IN 5
#define NH 15
#define NOUT 30
#define NOP 16            // o-pair slots per f: 15 real + 1 zero-pad lane

typedef float v2f __attribute__((ext_vector_type(2)));
typedef float v4f __attribute__((ext_vector_type(4)));

// rec2 layout: [f][j(0..3)][op(0..15)][4 floats] = 256 floats (1 KB) per f.
//   j=0: {bc0, bc1, w3_0, w3_1}   j=1: {Wc[0][o0],Wc[0][o1],Wc[1][o0],Wc[1][o1]}
//   j=2: {Wc[2][..],Wc[3][..]}    j=3: {Wc[4][o0],Wc[4][o1],0,0}; op==15 all zero.
__global__ __launch_bounds__(256) void precompute_kernel(
    const float* __restrict__ W1, const float* __restrict__ b1,
    const float* __restrict__ W2, const float* __restrict__ b2,
    const float* __restrict__ W3, float* __restrict__ rec2)
{
    const int idx = blockIdx.x * 256 + threadIdx.x;
    if (idx >= NF * NOP) return;
    const int f  = idx / NOP;
    const int op = idx - f * NOP;
    float* r = rec2 + (size_t)f * 256;

    if (op == 15) {
        #pragma unroll
        for (int j = 0; j < 4; ++j) {
            r[j * 64 + op * 4 + 0] = 0.f; r[j * 64 + op * 4 + 1] = 0.f;
            r[j * 64 + op * 4 + 2] = 0.f; r[j * 64 + op * 4 + 3] = 0.f;
        }
        return;
    }
    const int o0 = 2 * op, o1 = 2 * op + 1;
    float bcv[2], wc[D_IN][2];
    #pragma unroll
    for (int t = 0; t < 2; ++t) {
        const int o = (t == 0) ? o0 : o1;
        float s = b2[f * NOUT + o];
        #pragma unroll
        for (int h = 0; h < NH; ++h)
            s = fmaf(b1[f * NH + h], W2[(f * NH + h) * NOUT + o], s);
        bcv[t] = s;
        #pragma unroll
        for (int i = 0; i < D_IN; ++i) {
            float w = 0.f;
            #pragma unroll
            for (int h = 0; h < NH; ++h)
                w = fmaf(W1[(f * D_IN + i) * NH + h], W2[(f * NH + h) * NOUT + o], w);
            wc[i][t] = w;
        }
    }
    r[0 * 64 + op * 4 + 0] = bcv[0];   r[0 * 64 + op * 4 + 1] = bcv[1];
    r[0 * 64 + op * 4 + 2] = W3[f * NOUT + o0];
    r[0 * 64 + op * 4 + 3] = W3[f * NOUT + o1];
    r[1 * 64 + op * 4 + 0] = wc[0][0]; r[1 * 64 + op * 4 + 1] = wc[0][1];
    r[1 * 64 + op * 4 + 2] = wc[1][0]; r[1 * 64 + op * 4 + 3] = wc[1][1];
    r[2 * 64 + op * 4 + 0] = wc[2][0]; r[2 * 64 + op * 4 + 1] = wc[2][1];
    r[2 * 64 + op * 4 + 2] = wc[3][0]; r[2 * 64 + op * 4 + 3] = wc[3][1];
    r[3 * 64 + op * 4 + 0] = wc[4][0]; r[3 * 64 + op * 4 + 1] = wc[4][1];
    r[3 * 64 + op * 4 + 2] = 0.f;      r[3 * 64 + op * 4 + 3] = 0.f;
}

// ---------------- Main kernel ----------------
// Block 320 thr (5 waves) = 64 b x 20 f. Wave wv owns f's wv*4..wv*4+3 (all 64 b).
// Lane = (bsu 0..3, op 0..15): 4 b per quad-read, o-pair per lane.
// y staged coalesced global -> LDS transposed [e=(f,i)][b] with XOR-quad swizzle;
// weights staged linear. Hot loop: ds_read_b128 only + pk VALU. No s_load/global.
#define FPART 20
#define NPARTS 10

__global__ __launch_bounds__(320, 4) void mlp_kernel(
    const float* __restrict__ y, const float* __restrict__ rec2,
    const float* __restrict__ b3, float* __restrict__ out)
{
    __shared__ float shy[FPART * D_IN * 64];   // [e][b^sw] planes, 25.6 KB
    __shared__ v4f   shw[FPART * 4 * NOP];     // 20 KB
    __shared__ float red[5 * 64];              // cross-wave partials

    const int tid = threadIdx.x;
    const int b0  = blockIdx.x * 64;
    const int f0  = blockIdx.y * FPART;

    // ---- stage weights (linear copy, 1280 v4f)
    {
        const v4f* wsrc = (const v4f*)(rec2 + (size_t)f0 * 256);
        #pragma unroll
        for (int i = 0; i < 4; ++i) shw[tid + i * 320] = wsrc[tid + i * 320];
    }
    // ---- stage y transposed: thread t -> row b_loc = t/5, r = t%5; 5 float4 each
    {
        const int b_loc = tid / 5;
        const int r     = tid - b_loc * 5;
        const v4f* grow = (const v4f*)(y + (size_t)(b0 + b_loc) * (NF * D_IN) + f0 * (FPART * D_IN) / FPART * FPART);
        // (f0 * 100) floats into the row:
        const v4f* gr   = (const v4f*)(y + (size_t)(b0 + b_loc) * (NF * D_IN) + f0 * D_IN);
        (void)grow;
        #pragma unroll
        for (int it = 0; it < 5; ++it) {
            const int j = it * 5 + r;            // float4 index 0..24
            const v4f v = gr[j];
            #pragma unroll
            for (int c = 0; c < 4; ++c) {
                const int e  = j * 4 + c;        // element (f_local*5+i), 0..99
                const int sw = ((e >> 2) & 7) << 2;
                shy[e * 64 + (b_loc ^ sw)] = v[c];
            }
        }
    }
    __syncthreads();

    const int l   = tid & 63;
    const int wv  = tid >> 6;        // 0..4: f-group
    const int bsu = l >> 4;          // 0..3
    const int op  = l & 15;          // 0..15

    v2f acc[16];
    #pragma unroll
    for (int t = 0; t < 16; ++t) acc[t] = (v2f)0.f;

    #pragma unroll
    for (int k = 0; k < 4; ++k) {
        const int fl = wv * 4 + k;   // local f 0..19
        const v4f w0  = shw[(fl * 4 + 0) * NOP + op];
        const v4f w1  = shw[(fl * 4 + 1) * NOP + op];
        const v4f w2  = shw[(fl * 4 + 2) * NOP + op];
        const v4f w3q = shw[(fl * 4 + 3) * NOP + op];

        #pragma unroll
        for (int p = 0; p < 4; ++p) {
            const int bb = p * 16 + bsu * 4;
            v4f yq[5];
            #pragma unroll
            for (int i = 0; i < D_IN; ++i) {
                const int e  = fl * 5 + i;
                const int sw = ((e >> 2) & 7) << 2;
                yq[i] = *(const v4f*)&shy[e * 64 + (bb ^ sw)];
            }
            #pragma unroll
            for (int bl = 0; bl < 4; ++bl) {
                v2f z = (v2f){w0.x, w0.y} + yq[0][bl] * (v2f){w1.x, w1.y};
                z += yq[1][bl] * (v2f){w1.z, w1.w};
                z += yq[2][bl] * (v2f){w2.x, w2.y};
                z += yq[3][bl] * (v2f){w2.z, w2.w};
                z += yq[4][bl] * (v2f){w3q.x, w3q.y};
                z  = __builtin_elementwise_max(z, (v2f)0.0f);
                acc[p * 4 + bl] += z * (v2f){w0.z, w0.w};
            }
        }
    }

    // ---- reduce across the 16 op-lanes (butterfly within 16-lane groups)
    float s[16];
    #pragma unroll
    for (int t = 0; t < 16; ++t) {
        s[t] = acc[t].x + acc[t].y;
        #pragma unroll
        for (int m = 1; m < 16; m <<= 1)
            s[t] += __shfl_xor(s[t], m, 16);
    }
    if (op == 0) {
        #pragma unroll
        for (int t = 0; t < 16; ++t) {
            const int p = t >> 2, bl = t & 3;
            red[wv * 64 + p * 16 + bsu * 4 + bl] = s[t];
        }
    }
    __syncthreads();

    if (tid < 64) {
        float v = red[tid] + red[64 + tid] + red[128 + tid] + red[192 + tid] + red[256 + tid];
        if (blockIdx.y == 0) v += b3[0];
        atomicAdd(&out[b0 + tid], v);
    }
}

extern "C" void kernel_launch(void* const* d_in, const int* in_sizes, int n_in,
                              void* d_out, int out_size, void* d_ws, size_t ws_size,
                              hipStream_t stream) {
    const float* y  = (const float*)d_in[0];
    const float* W1 = (const float*)d_in[1];
    const float* b1 = (const float*)d_in[2];
    const float* W2 = (const float*)d_in[3];
    const float* b2 = (const float*)d_in[4];
    const float* W3 = (const float*)d_in[5];
    const float* b3 = (const float*)d_in[6];
    float* out = (float*)d_out;

    float* rec2 = (float*)d_ws;   // 200 * 256 floats = 204.8 KB

    hipMemsetAsync(out, 0, (size_t)B_TOTAL * sizeof(float), stream);
    precompute_kernel<<<(NF * NOP + 255) / 256, 256, 0, stream>>>(W1, b1, W2, b2, W3, rec2);
    mlp_kernel<<<dim3(B_TOTAL / 64, NPARTS), 320, 0, stream>>>(y, rec2, b3, out);
}

// Round 7
// 214.866 us; speedup vs baseline: 1.2600x; 1.1461x over previous
//
#include <hip/hip_runtime.h>

#define B_TOTAL 32768
#define NF 200
#define D_IN 5
#define NH 15
#define NOUT 30

typedef _Float16 half8 __attribute__((ext_vector_type(8)));
typedef _Float16 half4_t __attribute__((ext_vector_type(4)));
typedef float f32x4 __attribute__((ext_vector_type(4)));

// ws layout: Bc fp16 [f 200][half 2][n 16][k8]  (= 256 halfs/f, 102400 B)
//            w3T fp32 [part 10][w 4][n 16][slot 12] (7680 floats) at +102400 B
// Bc k8 per (f, o=half*16+n): {Wc[0..4][o], bc[o], 0, 0}; o>=30 rows all zero (ws pre-zeroed).
#define WS_BC_BYTES 102400
#define WS_TOTAL (102400 + 30720)

__global__ __launch_bounds__(256) void precompute_kernel(
    const float* __restrict__ W1, const float* __restrict__ b1,
    const float* __restrict__ W2, const float* __restrict__ b2,
    const float* __restrict__ W3, _Float16* __restrict__ Bc,
    float* __restrict__ w3T)
{
    const int idx = blockIdx.x * 256 + threadIdx.x;
    if (idx >= NF * 32) return;
    const int f  = idx >> 5;
    const int r  = idx & 31;
    const int hf = r >> 4;          // which 16-col half of the 30 outputs
    const int n  = r & 15;
    const int o  = hf * 16 + n;
    if (o >= NOUT) return;          // pad columns stay zero (ws memset)

    float bcv = b2[f * NOUT + o];
    #pragma unroll
    for (int h = 0; h < NH; ++h)
        bcv = fmaf(b1[f * NH + h], W2[(f * NH + h) * NOUT + o], bcv);
    float wc[D_IN];
    #pragma unroll
    for (int i = 0; i < D_IN; ++i) {
        float s = 0.f;
        #pragma unroll
        for (int h = 0; h < NH; ++h)
            s = fmaf(W1[(f * D_IN + i) * NH + h], W2[(f * NH + h) * NOUT + o], s);
        wc[i] = s;
    }
    _Float16* dst = Bc + (size_t)f * 256 + (hf * 16 + n) * 8;
    #pragma unroll
    for (int i = 0; i < D_IN; ++i) dst[i] = (_Float16)wc[i];
    dst[5] = (_Float16)bcv;   // pairs with the 1.0 bias slot in A
    dst[6] = (_Float16)0.f;
    dst[7] = (_Float16)0.f;

    const int p = f / 20, fl = f % 20, Kg = fl / 4, w = fl % 4;
    w3T[((size_t)(p * 4 + w) * 16 + n) * 12 + (Kg * 2 + hf)] = W3[f * NOUT + o];
}

// ---------------- Main kernel ----------------
// Block 256 thr (4 waves) = 64 b (4 M-tiles) x 20 f (5 K-groups of 4 f).
// Wave w handles f_local == w (mod 4). Per K-group: A-frag = 1 ds_read_b128
// (4 f-slots of 8 halfs: {y0..y4,1.0,0,0}), B-frags = b128 with zero-slot
// redirect for quads != w (block-diagonal). MFMA 16x16x32 f16, bias via the
// 1.0 A-column. Epilogue: relu*w3 into acc, 16-lane shfl reduce, atomicAdd.
#define FPART 20
#define NPARTS 10

__global__ __launch_bounds__(256, 4) void mlp_kernel(
    const float* __restrict__ y, const _Float16* __restrict__ Bc,
    const float* __restrict__ w3T, const float* __restrict__ b3,
    float* __restrict__ out)
{
    __shared__ __align__(16) _Float16 sy[64 * 168];   // [b][f-slot 20 x8 + pad8]
    __shared__ __align__(16) _Float16 sB[20 * 256];   // part's Bc, linear
    __shared__ __align__(16) float    sw3[4 * 16 * 12];
    __shared__ __align__(16) _Float16 szero[8];

    const int tid = threadIdx.x;
    const int b0  = blockIdx.x * 64;
    const int p   = blockIdx.y;
    const int f0  = p * FPART;

    if (tid < 8) szero[tid] = (_Float16)0.f;
    // stage B: 20*256 halfs = 640 float4
    {
        const f32x4* g = (const f32x4*)(Bc + (size_t)f0 * 256);
        f32x4* s = (f32x4*)sB;
        s[tid]       = g[tid];
        s[tid + 256] = g[tid + 256];
        if (tid < 128) s[tid + 512] = g[tid + 512];
    }
    // stage w3T: 768 floats = 192 float4
    if (tid < 192) ((f32x4*)sw3)[tid] = ((const f32x4*)w3T)[(size_t)p * 192 + tid];
    // stage y: 1280 (b,f) tasks; convert to fp16, bias 1.0 in slot 5
    #pragma unroll
    for (int it = 0; it < 5; ++it) {
        const int id = tid + it * 256;
        const int b  = id / 20;
        const int fl = id - b * 20;
        const float* src = y + (size_t)(b0 + b) * (NF * D_IN) + (size_t)(f0 + fl) * 5;
        const float v0 = src[0], v1 = src[1], v2 = src[2], v3 = src[3], v4 = src[4];
        half4_t h0, h1;
        h0[0] = (_Float16)v0; h0[1] = (_Float16)v1;
        h0[2] = (_Float16)v2; h0[3] = (_Float16)v3;
        h1[0] = (_Float16)v4; h1[1] = (_Float16)1.0f;
        h1[2] = (_Float16)0.f; h1[3] = (_Float16)0.f;
        *(half4_t*)&sy[b * 168 + fl * 8]     = h0;
        *(half4_t*)&sy[b * 168 + fl * 8 + 4] = h1;
    }
    __syncthreads();

    const int lane = tid & 63;
    const int w    = tid >> 6;       // wave id == f_in_group
    const int n    = lane & 15;      // A row m / B col n / C col
    const int q    = lane >> 4;      // quad == k-block == fig for A

    float acc[4][4];
    #pragma unroll
    for (int Mt = 0; Mt < 4; ++Mt)
        #pragma unroll
        for (int g = 0; g < 4; ++g) acc[Mt][g] = 0.f;

    #pragma unroll 1
    for (int Kg = 0; Kg < 5; ++Kg) {
        const int fl = Kg * 4 + w;   // this wave's f_local
        half8 A[4];
        #pragma unroll
        for (int Mt = 0; Mt < 4; ++Mt)
            A[Mt] = *(const half8*)&sy[(Mt * 16 + n) * 168 + (Kg * 4 + q) * 8];

        const _Float16* bp0 = (q == w) ? &sB[fl * 256 + n * 8]       : szero;
        const _Float16* bp1 = (q == w) ? &sB[fl * 256 + (16 + n) * 8] : szero;
        const half8 Bf0 = *(const half8*)bp0;
        const half8 Bf1 = *(const half8*)bp1;

        const float* w3p = &sw3[(w * 16 + n) * 12 + Kg * 2];
        const float w30 = w3p[0], w31 = w3p[1];

        #pragma unroll
        for (int Mt = 0; Mt < 4; ++Mt) {
            f32x4 c0 = {0.f, 0.f, 0.f, 0.f};
            f32x4 c1 = {0.f, 0.f, 0.f, 0.f};
            c0 = __builtin_amdgcn_mfma_f32_16x16x32_f16(A[Mt], Bf0, c0, 0, 0, 0);
            c1 = __builtin_amdgcn_mfma_f32_16x16x32_f16(A[Mt], Bf1, c1, 0, 0, 0);
            #pragma unroll
            for (int g = 0; g < 4; ++g)
                acc[Mt][g] += fmaxf(c0[g], 0.f) * w30 + fmaxf(c1[g], 0.f) * w31;
        }
    }

    // reduce over the 16 n-lanes (C cols) within each quad
    #pragma unroll
    for (int Mt = 0; Mt < 4; ++Mt)
        #pragma unroll
        for (int g = 0; g < 4; ++g) {
            float v = acc[Mt][g];
            v += __shfl_xor(v, 1, 16);
            v += __shfl_xor(v, 2, 16);
            v += __shfl_xor(v, 4, 16);
            v += __shfl_xor(v, 8, 16);
            acc[Mt][g] = v;
        }
    if (n == 0) {
        #pragma unroll
        for (int Mt = 0; Mt < 4; ++Mt)
            #pragma unroll
            for (int g = 0; g < 4; ++g) {
                const int b = b0 + Mt * 16 + q * 4 + g;   // C row = quad*4 + reg
                float v = acc[Mt][g];
                if (p == 0 && w == 0) v += b3[0];
                atomicAdd(&out[b], v);
            }
    }
}

extern "C" void kernel_launch(void* const* d_in, const int* in_sizes, int n_in,
                              void* d_out, int out_size, void* d_ws, size_t ws_size,
                              hipStream_t stream) {
    const float* y  = (const float*)d_in[0];
    const float* W1 = (const float*)d_in[1];
    const float* b1 = (const float*)d_in[2];
    const float* W2 = (const float*)d_in[3];
    const float* b2 = (const float*)d_in[4];
    const float* W3 = (const float*)d_in[5];
    const float* b3 = (const float*)d_in[6];
    float* out = (float*)d_out;

    _Float16* Bc  = (_Float16*)d_ws;
    float*    w3T = (float*)((char*)d_ws + WS_BC_BYTES);

    hipMemsetAsync(out, 0, (size_t)B_TOTAL * sizeof(float), stream);
    hipMemsetAsync(d_ws, 0, WS_TOTAL, stream);
    precompute_kernel<<<(NF * 32 + 255) / 256, 256, 0, stream>>>(W1, b1, W2, b2, W3, Bc, w3T);
    mlp_kernel<<<dim3(B_TOTAL / 64, NPARTS), 256, 0, stream>>>(y, Bc, w3T, b3, out);
}